// Round 10
// baseline (313.357 us; speedup 1.0000x reference)
//
#include <hip/hip_runtime.h>
#include <stdint.h>

// Hamming distance as an MX-FP4 MFMA GEMM.
// Token t -> 3 features (s1, s0, s1*s0), s=+-1, fp4 e2m1 (+1=0x2, -1=0xA),
// scales 1.0 (0x7F). dot = 4*matches - 512 => dist = 512 - ((dot+512)>>2).
//
// Packed layout (validated R6): pk[R(32 groups of 256 rows)][s_glob(24)][g(2)][r(256)][16B]
//   = group*196608 + s_glob*8192 + g*4096 + r*16, s_glob = K-chunk of 64 fp4.
//
// R10 = R9 + LDS-transposed epilogue: stores become 512-B contiguous row
// segments (int4 x 32 lanes) instead of 128-B dword scatters.

#define NROWS 8192

typedef int   v4i  __attribute__((ext_vector_type(4)));
typedef float v16f __attribute__((ext_vector_type(16)));

#define AS1(p) ((const __attribute__((address_space(1))) void*)(p))
#define AS3(p) ((__attribute__((address_space(3))) void*)(p))
#define PAD8(v) __builtin_shufflevector((v), (v), 0, 1, 2, 3, -1, -1, -1, -1)

// ---------------- pack (unchanged from R6; proven) --------------------------
__global__ __launch_bounds__(512) void pack_kernel(
    const int* __restrict__ xq, const int* __restrict__ xp,
    uint8_t* __restrict__ qpk, uint8_t* __restrict__ ppk) {
  __shared__ uint8_t lt[64 * 384];      // [rl(64)][c(3)][chunk(8)^swz][16B]
  const int bid = blockIdx.x;           // 512 = 128 R64 * 2 dh * 2 op
  const int op  = bid & 1;
  const int dh  = (bid >> 1) & 1;
  const int R64 = bid >> 2;
  const int t   = threadIdx.x;
  const int* src = op ? xp : xq;
  uint8_t*   dst = op ? ppk : qpk;
  const int row0 = R64 * 64;
  const int d0   = dh * 256;

  #pragma unroll
  for (int i = 0; i < 8; ++i) {
    const int idx = i * 512 + t;
    const int rl = idx >> 6, q = idx & 63;
    const int4 a = ((const int4*)(src + (size_t)(row0 + rl) * 512 + d0))[q];
    const int tok[4] = {a.x, a.y, a.z, a.w};
    uint32_t n0 = 0, n1 = 0, n2 = 0;
    #pragma unroll
    for (int j = 0; j < 4; ++j) {
      const uint32_t b1 = (tok[j] >> 1) & 1, b0 = tok[j] & 1;
      n0 |= (0x2u | (b1 << 3)) << (4 * j);
      n1 |= (0x2u | (b0 << 3)) << (4 * j);
      n2 |= (0x2u | ((b1 ^ b0) << 3)) << (4 * j);
    }
    uint8_t* p = lt + rl * 384 + (((q >> 3) ^ (rl & 7)) << 4) + (q & 7) * 2;
    *(uint16_t*)(p)       = (uint16_t)n0;
    *(uint16_t*)(p + 128) = (uint16_t)n1;
    *(uint16_t*)(p + 256) = (uint16_t)n2;
  }
  __syncthreads();

  const size_t Rg = R64 >> 2;
  const int rb = (R64 & 3) * 64;
  #pragma unroll
  for (int i = 0; i < 3; ++i) {
    const int o = i * 512 + t;
    const int c = o >> 9, sg = (o >> 6) & 7, rl = o & 63;
    const int kt = c * 2 + dh;
    const uint4 v = *(const uint4*)(lt + rl * 384 + c * 128 + ((sg ^ (rl & 7)) << 4));
    *(uint4*)(dst + (((Rg * 6 + kt) * 8 + sg) * 256 + rb + rl) * 16) = v;
  }
}

// ---------------- main GEMM -------------------------------------------------
__global__ __launch_bounds__(256, 3) void hamming_mfma(
    const uint8_t* __restrict__ Apk, const uint8_t* __restrict__ Bpk,
    int* __restrict__ out) {
  // ring chunk = [op(2)][pp(2)][g(2)][j(128)][16B] = 16 KiB; 3 chunks = 48 KiB
  __shared__ __align__(128) uint8_t lds[49152];

  const int t = threadIdx.x, l = t & 63, w = t >> 6;
  const int wr = w >> 1, wc = w & 1;           // wave -> 64x64 sub-tile
  const int g = l >> 5, ll = l & 31;

  // XCD swizzle (4096 % 8 == 0) + 8x8 patches: per-patch ops = 1.5 MB, L2-fit
  const int bid = blockIdx.x;
  const int nid = (bid & 7) * 512 + (bid >> 3);
  const int pch = nid >> 6, q = nid & 63;
  const int br = (pch >> 3) * 8 + (q >> 3);    // 0..63
  const int bc = (pch & 7) * 8 + (q & 7);      // 0..63

  // staging source: instr (op, pp) at chunk c reads
  //   base_op + (2c+pp)*8192 + g2*4096 + (rb_op + j)*16,  g2 = t>>7, j = t&127
  const int g2 = t >> 7, j = t & 127;
  const uint8_t* srcA = Apk + (size_t)(br >> 1) * 196608 + g2 * 4096
                      + ((br & 1) * 128 + j) * 16;
  const uint8_t* srcB = Bpk + (size_t)(bc >> 1) * 196608 + g2 * 4096
                      + ((bc & 1) * 128 + j) * 16;

  #define STAGE(c, buf) do {                                                   \
    __builtin_amdgcn_global_load_lds(AS1(srcA + (2*(c))   * 8192),             \
        AS3(lds + (buf) * 16384 +  0   + t * 16), 16, 0, 0);                   \
    __builtin_amdgcn_global_load_lds(AS1(srcA + (2*(c)+1) * 8192),             \
        AS3(lds + (buf) * 16384 + 4096 + t * 16), 16, 0, 0);                   \
    __builtin_amdgcn_global_load_lds(AS1(srcB + (2*(c))   * 8192),             \
        AS3(lds + (buf) * 16384 + 8192 + t * 16), 16, 0, 0);                   \
    __builtin_amdgcn_global_load_lds(AS1(srcB + (2*(c)+1) * 8192),             \
        AS3(lds + (buf) * 16384 + 12288 + t * 16), 16, 0, 0);                  \
  } while (0)

  v16f acc[2][2] = {};

  STAGE(0, 0);
  STAGE(1, 1);

  const int aoff = g * 2048 + (wr * 64 + ll) * 16;   // + m*512, + pp*4096
  const int boff = 8192 + g * 2048 + (wc * 64 + ll) * 16;

  #pragma unroll
  for (int c = 0; c < 12; ++c) {
    const int buf = c % 3;
    if (c == 11) asm volatile("s_waitcnt vmcnt(0)" ::: "memory");
    else         asm volatile("s_waitcnt vmcnt(4)" ::: "memory");
    __builtin_amdgcn_s_barrier();
    if (c < 10) STAGE(c + 2, (c + 2) % 3);

    const uint8_t* La = lds + buf * 16384;
    v4i af[2][2], bf[2][2];
    #pragma unroll
    for (int pp = 0; pp < 2; ++pp) {
      #pragma unroll
      for (int m = 0; m < 2; ++m)
        af[pp][m] = *(const v4i*)(La + pp * 4096 + aoff + m * 512);
      #pragma unroll
      for (int n = 0; n < 2; ++n)
        bf[pp][n] = *(const v4i*)(La + pp * 4096 + boff + n * 512);
    }
    asm volatile("s_waitcnt lgkmcnt(0)" ::: "memory");
    __builtin_amdgcn_sched_barrier(0);
    __builtin_amdgcn_s_setprio(1);
    #pragma unroll
    for (int pp = 0; pp < 2; ++pp)
      #pragma unroll
      for (int m = 0; m < 2; ++m)
        #pragma unroll
        for (int n = 0; n < 2; ++n) {
          acc[m][n] = __builtin_amdgcn_mfma_scale_f32_32x32x64_f8f6f4(
              PAD8(af[pp][m]), PAD8(bf[pp][n]), acc[m][n],
              4 /*fp4 A*/, 4 /*fp4 B*/, 0, 0x7F7F7F7F, 0, 0x7F7F7F7F);
        }
    __builtin_amdgcn_s_setprio(0);
    __builtin_amdgcn_s_barrier();
  }

  // ---- epilogue: LDS-transpose then 512-B contiguous int4 row stores ------
  // li[64][132] ints (pad 4 -> conflict-free); half h = row band [h*64, h*64+64)
  int* li = (int*)lds;
  const int rr = t >> 5;                 // 0..7
  const int cc = (t & 31) * 4;           // 0..124
  #pragma unroll
  for (int h = 0; h < 2; ++h) {
    __syncthreads();                     // prior LDS use complete
    if (wr == h) {
      #pragma unroll
      for (int m = 0; m < 2; ++m)
        #pragma unroll
        for (int n = 0; n < 2; ++n)
          #pragma unroll
          for (int reg = 0; reg < 16; ++reg) {
            const int rloc = m * 32 + (reg & 3) + 8 * (reg >> 2) + 4 * g;
            li[rloc * 132 + wc * 64 + n * 32 + ll] =
                512 - (((int)acc[m][n][reg] + 512) >> 2);
          }
    }
    __syncthreads();
    #pragma unroll
    for (int k = 0; k < 8; ++k) {
      const int rloc = k * 8 + rr;
      const int4 v = *(const int4*)(li + rloc * 132 + cc);
      *(int4*)(out + (size_t)(br * 128 + h * 64 + rloc) * NROWS + bc * 128 + cc) = v;
    }
  }
}

extern "C" void kernel_launch(void* const* d_in, const int* in_sizes, int n_in,
                              void* d_out, int out_size, void* d_ws, size_t ws_size,
                              hipStream_t stream) {
  const int* xq = (const int*)d_in[0];
  const int* xp = (const int*)d_in[1];
  int* out = (int*)d_out;

  uint8_t* qpk = (uint8_t*)d_ws;                       // 6 MB
  uint8_t* ppk = qpk + (size_t)NROWS * 768;            // 6 MB

  pack_kernel<<<512, 512, 0, stream>>>(xq, xp, qpk, ppk);
  hamming_mfma<<<4096, 256, 0, stream>>>(qpk, ppk, out);
}